// Round 1
// baseline (644.806 us; speedup 1.0000x reference)
//
#include <hip/hip_runtime.h>

#define HW 128
#define CIN 256
#define DIM 128
#define PLANES 64
#define EPSBN 1e-5f

// -------------------------------------------------------------------------
// Kernel 1: fc1 (1x1 conv 256->128) over the whole map.
// Output layout channel-last: xout[b][h][w][o], o contiguous (for K2 gathers).
// Block: 256 threads, tile = 64 positions x 128 outputs, K staged in chunks of 64.
// -------------------------------------------------------------------------
__global__ __launch_bounds__(256)
void fc1_kernel(const float* __restrict__ feat,   // [8][256][16384]
                const float* __restrict__ w,      // [128][256]
                const float* __restrict__ bias,   // [128]
                float* __restrict__ xout) {       // [8][16384][128]
    __shared__ float ftile[64][64];       // [k][pos]
    __shared__ float wtile[128][65];      // [o][k], +1 pad

    const int tid = threadIdx.x;
    const int b  = blockIdx.x >> 8;
    const int p0 = (blockIdx.x & 255) * 64;
    const int og = tid & 15;      // o = og + 16*j  (16 distinct banks per read)
    const int po = tid >> 4;      // pos = p0 + po*4 + i

    float acc[8][4];
    #pragma unroll
    for (int j = 0; j < 8; ++j)
        #pragma unroll
        for (int i = 0; i < 4; ++i) acc[j][i] = 0.f;

    for (int kc = 0; kc < 4; ++kc) {
        // stage feature tile: 64 channels x 64 positions
        #pragma unroll
        for (int jj = 0; jj < 4; ++jj) {
            const int idx = tid + 256 * jj;
            const int row = idx >> 4, col = (idx & 15) * 4;
            const float4 v = *(const float4*)&feat[(((size_t)(b * CIN + kc * 64 + row)) << 14) + p0 + col];
            *(float4*)&ftile[row][col] = v;
        }
        // stage weight tile: 128 outputs x 64 k
        #pragma unroll
        for (int jj = 0; jj < 8; ++jj) {
            const int idx = tid + 256 * jj;
            const int row = idx >> 4, col = (idx & 15) * 4;
            const float4 v = *(const float4*)&w[row * 256 + kc * 64 + col];
            wtile[row][col + 0] = v.x; wtile[row][col + 1] = v.y;
            wtile[row][col + 2] = v.z; wtile[row][col + 3] = v.w;
        }
        __syncthreads();

        #pragma unroll 4
        for (int k = 0; k < 64; ++k) {
            const float4 f = *(const float4*)&ftile[k][po * 4];
            #pragma unroll
            for (int j = 0; j < 8; ++j) {
                const float wv = wtile[og + 16 * j][k];
                acc[j][0] += wv * f.x; acc[j][1] += wv * f.y;
                acc[j][2] += wv * f.z; acc[j][3] += wv * f.w;
            }
        }
        __syncthreads();
    }

    #pragma unroll
    for (int i = 0; i < 4; ++i) {
        const int p = p0 + po * 4 + i;
        const size_t base = ((((size_t)b) << 14) + p) * 128;
        #pragma unroll
        for (int j = 0; j < 8; ++j) {
            const int o = og + 16 * j;
            xout[base + o] = acc[j][i] + bias[o];
        }
    }
}

// -------------------------------------------------------------------------
// Kernel 2: sampling + maxpool + bottleneck + fc2.  One block = 4 lines.
// -------------------------------------------------------------------------
__global__ __launch_bounds__(256)
void loi_kernel(const float* __restrict__ x,       // [8][128][128][128] ch-last
                const float* __restrict__ lines,   // [16384][4] (x0,y0,x1,y1)
                const float* __restrict__ bn1g, const float* __restrict__ bn1b,
                const float* __restrict__ bn1m, const float* __restrict__ bn1v,
                const float* __restrict__ w1,  const float* __restrict__ b1,
                const float* __restrict__ bn2g, const float* __restrict__ bn2b,
                const float* __restrict__ bn2m, const float* __restrict__ bn2v,
                const float* __restrict__ w2,  const float* __restrict__ b2,
                const float* __restrict__ bn3g, const float* __restrict__ bn3b,
                const float* __restrict__ bn3m, const float* __restrict__ bn3v,
                const float* __restrict__ w3,  const float* __restrict__ b3,
                const float* __restrict__ fc2w, const float* __restrict__ fc2b,
                float* __restrict__ out) {
    __shared__ float xp  [4][128][8];
    __shared__ float bufA[4][128][8];
    __shared__ float bufB[4][64][8];
    __shared__ float s1[128], t1[128], s2[64], t2[64], s3[64], t3[64];

    const int tid = threadIdx.x;

    // BN eval-mode LUTs
    if (tid < 128) {
        const float s = bn1g[tid] * rsqrtf(bn1v[tid] + EPSBN);
        s1[tid] = s; t1[tid] = bn1b[tid] - bn1m[tid] * s;
    } else if (tid < 192) {
        const int c = tid - 128;
        const float s = bn2g[c] * rsqrtf(bn2v[c] + EPSBN);
        s2[c] = s; t2[c] = bn2b[c] - bn2m[c] * s;
    } else {
        const int c = tid - 192;
        const float s = bn3g[c] * rsqrtf(bn3v[c] + EPSBN);
        s3[c] = s; t3[c] = bn3b[c] - bn3m[c] * s;
    }

    // ---- Phase A: bilinear sample 32 pts, maxpool by 4 -> xp[li][c][8] ----
    {
        const int c    = tid & 127;
        const int lsub = tid >> 7;
        for (int lp = 0; lp < 2; ++lp) {
            const int li = lp * 2 + lsub;
            const int gl = blockIdx.x * 4 + li;
            const int b  = gl >> 11;
            const float4 ln = *(const float4*)&lines[gl * 4];
            const float* xb = x + (((size_t)b) << 14) * 128;
            float mreg[8];
            #pragma unroll
            for (int t = 0; t < 8; ++t) {
                float m = -3.4e38f;
                #pragma unroll
                for (int s = 0; s < 4; ++s) {
                    const int p = t * 4 + s;
                    const float lam = (float)p * (1.0f / 31.0f);
                    const float px = ln.x * lam + ln.z * (1.f - lam) - 0.5f;
                    const float py = ln.y * lam + ln.w * (1.f - lam) - 0.5f;
                    const float px0 = fminf(fmaxf(floorf(px), 0.f), 127.f);
                    const float py0 = fminf(fmaxf(floorf(py), 0.f), 127.f);
                    const float px1 = fminf(px0 + 1.f, 127.f);
                    const float py1 = fminf(py0 + 1.f, 127.f);
                    const int ix0 = (int)px0, iy0 = (int)py0;
                    const int ix1 = (int)px1, iy1 = (int)py1;
                    const float wx1 = px1 - px, wx0 = px - px0;
                    const float wy1 = py1 - py, wy0 = py - py0;
                    const float g00 = xb[((ix0 << 7) + iy0) * 128 + c];
                    const float g10 = xb[((ix1 << 7) + iy0) * 128 + c];
                    const float g01 = xb[((ix0 << 7) + iy1) * 128 + c];
                    const float g11 = xb[((ix1 << 7) + iy1) * 128 + c];
                    const float v = g00 * (wx1 * wy1) + g10 * (wx0 * wy1)
                                  + g01 * (wx1 * wy0) + g11 * (wx0 * wy0);
                    m = fmaxf(m, v);
                }
                mreg[t] = m;
            }
            *(float4*)&xp[li][c][0] = make_float4(mreg[0], mreg[1], mreg[2], mreg[3]);
            *(float4*)&xp[li][c][4] = make_float4(mreg[4], mreg[5], mreg[6], mreg[7]);
        }
    }
    __syncthreads();

    // ---- h1 = relu(bn1(xp)) -> bufA ----
    #pragma unroll
    for (int j = 0; j < 4; ++j) {
        const int i4 = tid + 256 * j;          // 0..1023 float4-units
        const int li2 = i4 >> 8;
        const int cc  = (i4 >> 1) & 127;
        const int th  = (i4 & 1) * 4;
        float4 v = *(const float4*)&xp[li2][cc][th];
        const float s = s1[cc], t0 = t1[cc];
        v.x = fmaxf(v.x * s + t0, 0.f); v.y = fmaxf(v.y * s + t0, 0.f);
        v.z = fmaxf(v.z * s + t0, 0.f); v.w = fmaxf(v.w * s + t0, 0.f);
        *(float4*)&bufA[li2][cc][th] = v;
    }
    __syncthreads();

    const int lane = tid & 63;
    const int li   = tid >> 6;

    // ---- conv1 (64x128) + bn2 + relu -> bufB ----
    {
        float a[8] = {0, 0, 0, 0, 0, 0, 0, 0};
        const float* w1row = w1 + lane * 128;
        for (int cc = 0; cc < 128; cc += 4) {
            const float4 wv = *(const float4*)&w1row[cc];
            const float wq[4] = {wv.x, wv.y, wv.z, wv.w};
            #pragma unroll
            for (int q = 0; q < 4; ++q) {
                const float4 lo = *(const float4*)&bufA[li][cc + q][0];
                const float4 hi = *(const float4*)&bufA[li][cc + q][4];
                a[0] += wq[q] * lo.x; a[1] += wq[q] * lo.y;
                a[2] += wq[q] * lo.z; a[3] += wq[q] * lo.w;
                a[4] += wq[q] * hi.x; a[5] += wq[q] * hi.y;
                a[6] += wq[q] * hi.z; a[7] += wq[q] * hi.w;
            }
        }
        const float bb = b1[lane], s = s2[lane], t0 = t2[lane];
        float r[8];
        #pragma unroll
        for (int t = 0; t < 8; ++t) r[t] = fmaxf((a[t] + bb) * s + t0, 0.f);
        *(float4*)&bufB[li][lane][0] = make_float4(r[0], r[1], r[2], r[3]);
        *(float4*)&bufB[li][lane][4] = make_float4(r[4], r[5], r[6], r[7]);
    }
    __syncthreads();

    // ---- conv2 (64x64, k=3, pad=1) + bn3 + relu -> bufA[0..63] ----
    {
        float a2[8] = {0, 0, 0, 0, 0, 0, 0, 0};
        for (int i = 0; i < 64; ++i) {
            const float4 lo = *(const float4*)&bufB[li][i][0];
            const float4 hi = *(const float4*)&bufB[li][i][4];
            const float* wr = w2 + ((size_t)(lane * 64 + i)) * 3;
            const float wk0 = wr[0], wk1 = wr[1], wk2 = wr[2];
            a2[0] += wk1 * lo.x + wk2 * lo.y;
            a2[1] += wk0 * lo.x + wk1 * lo.y + wk2 * lo.z;
            a2[2] += wk0 * lo.y + wk1 * lo.z + wk2 * lo.w;
            a2[3] += wk0 * lo.z + wk1 * lo.w + wk2 * hi.x;
            a2[4] += wk0 * lo.w + wk1 * hi.x + wk2 * hi.y;
            a2[5] += wk0 * hi.x + wk1 * hi.y + wk2 * hi.z;
            a2[6] += wk0 * hi.y + wk1 * hi.z + wk2 * hi.w;
            a2[7] += wk0 * hi.z + wk1 * hi.w;
        }
        const float bb = b2[lane], s = s3[lane], t0 = t3[lane];
        float r[8];
        #pragma unroll
        for (int t = 0; t < 8; ++t) r[t] = fmaxf((a2[t] + bb) * s + t0, 0.f);
        *(float4*)&bufA[li][lane][0] = make_float4(r[0], r[1], r[2], r[3]);
        *(float4*)&bufA[li][lane][4] = make_float4(r[4], r[5], r[6], r[7]);
    }
    __syncthreads();

    // ---- conv3 (128x64) + residual + relu + fc2 dot ----
    {
        float a3[8] = {0, 0, 0, 0, 0, 0, 0, 0};
        float a4[8] = {0, 0, 0, 0, 0, 0, 0, 0};
        const float* w3a = w3 + lane * 64;
        const float* w3b = w3 + (lane + 64) * 64;
        for (int i = 0; i < 64; i += 4) {
            const float4 wa = *(const float4*)&w3a[i];
            const float4 wb = *(const float4*)&w3b[i];
            const float waq[4] = {wa.x, wa.y, wa.z, wa.w};
            const float wbq[4] = {wb.x, wb.y, wb.z, wb.w};
            #pragma unroll
            for (int q = 0; q < 4; ++q) {
                const float4 lo = *(const float4*)&bufA[li][i + q][0];
                const float4 hi = *(const float4*)&bufA[li][i + q][4];
                a3[0] += waq[q] * lo.x; a3[1] += waq[q] * lo.y;
                a3[2] += waq[q] * lo.z; a3[3] += waq[q] * lo.w;
                a3[4] += waq[q] * hi.x; a3[5] += waq[q] * hi.y;
                a3[6] += waq[q] * hi.z; a3[7] += waq[q] * hi.w;
                a4[0] += wbq[q] * lo.x; a4[1] += wbq[q] * lo.y;
                a4[2] += wbq[q] * lo.z; a4[3] += wbq[q] * lo.w;
                a4[4] += wbq[q] * hi.x; a4[5] += wbq[q] * hi.y;
                a4[6] += wbq[q] * hi.z; a4[7] += wbq[q] * hi.w;
            }
        }
        float partial = 0.f;
        const float ba = b3[lane], bbb = b3[lane + 64];
        #pragma unroll
        for (int t = 0; t < 8; ++t) {
            float v1 = xp[li][lane][t] + a3[t] + ba;
            v1 = fmaxf(v1, 0.f);
            partial += v1 * fc2w[lane * 8 + t];
            float v2 = xp[li][lane + 64][t] + a4[t] + bbb;
            v2 = fmaxf(v2, 0.f);
            partial += v2 * fc2w[(lane + 64) * 8 + t];
        }
        #pragma unroll
        for (int off = 32; off > 0; off >>= 1)
            partial += __shfl_down(partial, off, 64);
        if (lane == 0) out[blockIdx.x * 4 + li] = partial + fc2b[0];
    }
}

// -------------------------------------------------------------------------
extern "C" void kernel_launch(void* const* d_in, const int* in_sizes, int n_in,
                              void* d_out, int out_size, void* d_ws, size_t ws_size,
                              hipStream_t stream) {
    const float* feature = (const float*)d_in[0];
    const float* lines   = (const float*)d_in[1];
    const float* fc1_w   = (const float*)d_in[2];
    const float* fc1_b   = (const float*)d_in[3];
    const float* bn1g    = (const float*)d_in[4];
    const float* bn1b    = (const float*)d_in[5];
    const float* bn1m    = (const float*)d_in[6];
    const float* bn1v    = (const float*)d_in[7];
    const float* w1      = (const float*)d_in[8];
    const float* b1      = (const float*)d_in[9];
    const float* bn2g    = (const float*)d_in[10];
    const float* bn2b    = (const float*)d_in[11];
    const float* bn2m    = (const float*)d_in[12];
    const float* bn2v    = (const float*)d_in[13];
    const float* w2      = (const float*)d_in[14];
    const float* b2      = (const float*)d_in[15];
    const float* bn3g    = (const float*)d_in[16];
    const float* bn3b    = (const float*)d_in[17];
    const float* bn3m    = (const float*)d_in[18];
    const float* bn3v    = (const float*)d_in[19];
    const float* w3      = (const float*)d_in[20];
    const float* b3      = (const float*)d_in[21];
    const float* fc2w    = (const float*)d_in[22];
    const float* fc2b    = (const float*)d_in[23];

    float* xmap = (float*)d_ws;   // needs 8*16384*128*4 = 64 MiB of workspace

    fc1_kernel<<<2048, 256, 0, stream>>>(feature, fc1_w, fc1_b, xmap);
    loi_kernel<<<4096, 256, 0, stream>>>(xmap, lines,
                                         bn1g, bn1b, bn1m, bn1v, w1, b1,
                                         bn2g, bn2b, bn2m, bn2v, w2, b2,
                                         bn3g, bn3b, bn3m, bn3v, w3, b3,
                                         fc2w, fc2b, (float*)d_out);
}

// Round 2
// 483.248 us; speedup vs baseline: 1.3343x; 1.3343x over previous
//
#include <hip/hip_runtime.h>

#define EPSBN 1e-5f

typedef _Float16 f16;
typedef _Float16 f16x8 __attribute__((ext_vector_type(8)));
typedef _Float16 f16x2 __attribute__((ext_vector_type(2)));
typedef float    f32x4 __attribute__((ext_vector_type(4)));

__device__ inline unsigned int pack2(float a, float b) {
    union { f16x2 h; unsigned int u; } cv;
    cv.h[0] = (f16)a; cv.h[1] = (f16)b;
    return cv.u;
}

// -------------------------------------------------------------------------
// Kernel 0: convert fc1 weights fp32 -> f16 [128][256] into workspace.
// -------------------------------------------------------------------------
__global__ void wprep_kernel(const float* __restrict__ w, f16* __restrict__ w16) {
    const int i = blockIdx.x * 256 + threadIdx.x;   // 32768 total
    w16[i] = (f16)w[i];
}

// -------------------------------------------------------------------------
// Kernel 1: fc1 via f16 MFMA.  C[o][p] = sum_k W[o][k] * F[k][p].
// Block: 256 thr (4 waves), tile M=128 (all o) x N=128 p, K=256 in 4 chunks.
// F staged transposed into LDS as f16 pairs, XOR-swizzled:
//   dword addr = p*32 + (kdw ^ (((p>>3)&7)<<2)), kdw = k_local/2.
// Wave w computes m-tiles {2w, 2w+1} x all 8 n-tiles.
// Output channel-last f16: xmap[b][p][o].
// -------------------------------------------------------------------------
__global__ __launch_bounds__(256)
void fc1_mfma(const float* __restrict__ feat,   // [8][256][16384]
              const f16*   __restrict__ w16,    // [128][256]
              const float* __restrict__ bias,   // [128]
              f16*         __restrict__ xmap) { // [8][16384][128]
    __shared__ unsigned int ft[128 * 32];       // 16 KB

    const int tid  = threadIdx.x;
    const int wv   = tid >> 6;
    const int lane = tid & 63;
    const int b    = blockIdx.x >> 7;
    const int p0   = (blockIdx.x & 127) * 128;
    const int n    = lane & 15;
    const int quad = lane >> 4;
    // staging ids: q = p-quad (0..31), r0 = k-pair base (0..7)
    const int q   = tid & 31;
    const int r0  = tid >> 5;
    const int swz = ((q >> 1) & 7) << 2;        // == (((4q+i)>>3)&7)<<2 for i<4

    f32x4 acc[2][8];
    #pragma unroll
    for (int mt = 0; mt < 2; ++mt)
        #pragma unroll
        for (int nt = 0; nt < 8; ++nt)
            acc[mt][nt] = (f32x4){0.f, 0.f, 0.f, 0.f};

    const float4* f4 = (const float4*)feat;

    for (int kc = 0; kc < 4; ++kc) {
        // ---- stage F chunk [64 k][128 p] -> ft (transposed, f16 pairs) ----
        #pragma unroll
        for (int j = 0; j < 4; ++j) {
            const int r = r0 + 8 * j;                       // k-pair index 0..31
            const size_t rowb = ((size_t)(b * 256 + kc * 64 + 2 * r)) << 12; // *4096 float4
            const float4 f0 = f4[rowb + (p0 >> 2) + q];
            const float4 f1 = f4[rowb + 4096 + (p0 >> 2) + q];
            const float fa0[4] = {f0.x, f0.y, f0.z, f0.w};
            const float fa1[4] = {f1.x, f1.y, f1.z, f1.w};
            #pragma unroll
            for (int i = 0; i < 4; ++i) {
                const int p = 4 * q + i;
                ft[p * 32 + (r ^ swz)] = pack2(fa0[i], fa1[i]);
            }
        }
        __syncthreads();

        // ---- MFMA over 2 k32 steps ----
        #pragma unroll
        for (int s = 0; s < 2; ++s) {
            const int kg = kc * 64 + s * 32 + quad * 8;
            const f16x8 a0 = *(const f16x8*)&w16[(wv * 32 + n) * 256 + kg];
            const f16x8 a1 = *(const f16x8*)&w16[(wv * 32 + 16 + n) * 256 + kg];
            #pragma unroll
            for (int nt = 0; nt < 8; ++nt) {
                const int p  = nt * 16 + n;
                const int sw = ((p >> 3) & 7) << 2;
                const f16x8 bf = *(const f16x8*)&ft[p * 32 + ((s * 16 + quad * 4) ^ sw)];
                acc[0][nt] = __builtin_amdgcn_mfma_f32_16x16x32_f16(a0, bf, acc[0][nt], 0, 0, 0);
                acc[1][nt] = __builtin_amdgcn_mfma_f32_16x16x32_f16(a1, bf, acc[1][nt], 0, 0, 0);
            }
        }
        __syncthreads();
    }

    // ---- epilogue: C/D layout col=lane&15 (=n=p), row=quad*4+r (=o) ----
    #pragma unroll
    for (int mt = 0; mt < 2; ++mt) {
        const int mrow = (wv * 2 + mt) * 16 + quad * 4;
        const float b0 = bias[mrow + 0], b1 = bias[mrow + 1];
        const float b2 = bias[mrow + 2], b3 = bias[mrow + 3];
        #pragma unroll
        for (int nt = 0; nt < 8; ++nt) {
            const int p = p0 + nt * 16 + n;
            const f32x4 a = acc[mt][nt];
            uint2 u2;
            u2.x = pack2(a[0] + b0, a[1] + b1);
            u2.y = pack2(a[2] + b2, a[3] + b3);
            *(uint2*)&xmap[((size_t)((b << 14) + p)) * 128 + mrow] = u2;
        }
    }
}

// -------------------------------------------------------------------------
// Kernel 2: sampling + maxpool + bottleneck + fc2.  One block = 4 lines.
// Thread (li = tid>>6, lane = tid&63) owns channels 2*lane, 2*lane+1.
// Interp tuples (offsets+weights) precomputed once per (li,pt) in LDS.
// xp kept in registers (m0/m1) for the residual.
// -------------------------------------------------------------------------
__global__ __launch_bounds__(256)
void loi_kernel(const f16*   __restrict__ x,       // [8][16384][128] ch-last f16
                const float* __restrict__ lines,   // [16384][4]
                const float* __restrict__ bn1g, const float* __restrict__ bn1b,
                const float* __restrict__ bn1m, const float* __restrict__ bn1v,
                const float* __restrict__ w1,  const float* __restrict__ b1,
                const float* __restrict__ bn2g, const float* __restrict__ bn2b,
                const float* __restrict__ bn2m, const float* __restrict__ bn2v,
                const float* __restrict__ w2,  const float* __restrict__ b2,
                const float* __restrict__ bn3g, const float* __restrict__ bn3b,
                const float* __restrict__ bn3m, const float* __restrict__ bn3v,
                const float* __restrict__ w3,  const float* __restrict__ b3,
                const float* __restrict__ fc2w, const float* __restrict__ fc2b,
                float* __restrict__ out) {
    __shared__ float poolA[4][8][128];   // conv1 input [li][t][c]; reused as conv2 out
    __shared__ float bufB [4][64][8];    // conv1 out [li][o][t]
    __shared__ float s1[128], t1[128], s2[64], t2[64], s3[64], t3[64];
    __shared__ int   toff[128][4];
    __shared__ float twgt[128][4];

    const int tid = threadIdx.x;

    // BN LUTs
    if (tid < 128) {
        const float s = bn1g[tid] * rsqrtf(bn1v[tid] + EPSBN);
        s1[tid] = s; t1[tid] = bn1b[tid] - bn1m[tid] * s;
    } else if (tid < 192) {
        const int c = tid - 128;
        const float s = bn2g[c] * rsqrtf(bn2v[c] + EPSBN);
        s2[c] = s; t2[c] = bn2b[c] - bn2m[c] * s;
    } else {
        const int c = tid - 192;
        const float s = bn3g[c] * rsqrtf(bn3v[c] + EPSBN);
        s3[c] = s; t3[c] = bn3b[c] - bn3m[c] * s;
    }

    // interp tuples: one per (li, pt)
    if (tid < 128) {
        const int li = tid >> 5, pt = tid & 31;
        const int gl = blockIdx.x * 4 + li;
        const float4 ln = *(const float4*)&lines[gl * 4];
        const float lam = (float)pt * (1.0f / 31.0f);
        const float px = ln.x * lam + ln.z * (1.f - lam) - 0.5f;
        const float py = ln.y * lam + ln.w * (1.f - lam) - 0.5f;
        const float px0 = fminf(fmaxf(floorf(px), 0.f), 127.f);
        const float py0 = fminf(fmaxf(floorf(py), 0.f), 127.f);
        const float px1 = fminf(px0 + 1.f, 127.f);
        const float py1 = fminf(py0 + 1.f, 127.f);
        const int ix0 = (int)px0, iy0 = (int)py0;
        const int ix1 = (int)px1, iy1 = (int)py1;
        toff[tid][0] = (((ix0 << 7) + iy0) << 7);   // f16-units: pix*128
        toff[tid][1] = (((ix1 << 7) + iy0) << 7);
        toff[tid][2] = (((ix0 << 7) + iy1) << 7);
        toff[tid][3] = (((ix1 << 7) + iy1) << 7);
        const float wx1 = px1 - px, wx0 = px - px0;
        const float wy1 = py1 - py, wy0 = py - py0;
        twgt[tid][0] = wx1 * wy1; twgt[tid][1] = wx0 * wy1;
        twgt[tid][2] = wx1 * wy0; twgt[tid][3] = wx0 * wy0;
    }
    __syncthreads();

    const int lane = tid & 63, li = tid >> 6;
    const int gl4  = blockIdx.x * 4 + li;
    const f16* xbh = x + ((size_t)(gl4 >> 11) << 21);   // + b*16384*128
    const int c0 = 2 * lane, c1 = 2 * lane + 1;

    // ---- Phase A: bilinear sample + maxpool(4), channels c0,c1 in regs ----
    float m0[8], m1[8];
    #pragma unroll
    for (int t = 0; t < 8; ++t) { m0[t] = -3.4e38f; m1[t] = -3.4e38f; }
    #pragma unroll
    for (int t = 0; t < 8; ++t) {
        #pragma unroll
        for (int s = 0; s < 4; ++s) {
            const int pt = t * 4 + s;
            const int4   off = *(const int4*)&toff[li * 32 + pt][0];
            const float4 wg  = *(const float4*)&twgt[li * 32 + pt][0];
            const f16x2 g00 = *(const f16x2*)(xbh + off.x + c0);
            const f16x2 g10 = *(const f16x2*)(xbh + off.y + c0);
            const f16x2 g01 = *(const f16x2*)(xbh + off.z + c0);
            const f16x2 g11 = *(const f16x2*)(xbh + off.w + c0);
            const float v0 = (float)g00[0] * wg.x + (float)g10[0] * wg.y
                           + (float)g01[0] * wg.z + (float)g11[0] * wg.w;
            const float v1 = (float)g00[1] * wg.x + (float)g10[1] * wg.y
                           + (float)g01[1] * wg.z + (float)g11[1] * wg.w;
            m0[t] = fmaxf(m0[t], v0);
            m1[t] = fmaxf(m1[t], v1);
        }
    }

    // ---- bufA0 = relu(bn1(xp)), layout [li][t][c] for conflict-free writes ----
    {
        const float sa = s1[c0], ta = t1[c0];
        const float sb = s1[c1], tb = t1[c1];
        #pragma unroll
        for (int t = 0; t < 8; ++t) {
            float2 v;
            v.x = fmaxf(m0[t] * sa + ta, 0.f);
            v.y = fmaxf(m1[t] * sb + tb, 0.f);
            *(float2*)&poolA[li][t][c0] = v;
        }
    }
    __syncthreads();

    // ---- conv1 (64x128) + bn2 + relu -> bufB[li][o][t] ----
    {
        float a[8] = {0, 0, 0, 0, 0, 0, 0, 0};
        const float* w1row = w1 + lane * 128;
        for (int cq = 0; cq < 32; ++cq) {
            const float4 wv4 = *(const float4*)&w1row[cq * 4];
            #pragma unroll
            for (int t = 0; t < 8; ++t) {
                const float4 av = *(const float4*)&poolA[li][t][cq * 4];
                a[t] += wv4.x * av.x + wv4.y * av.y + wv4.z * av.z + wv4.w * av.w;
            }
        }
        const float bb = b1[lane], s = s2[lane], t0 = t2[lane];
        float r[8];
        #pragma unroll
        for (int t = 0; t < 8; ++t) r[t] = fmaxf((a[t] + bb) * s + t0, 0.f);
        *(float4*)&bufB[li][lane][0] = make_float4(r[0], r[1], r[2], r[3]);
        *(float4*)&bufB[li][lane][4] = make_float4(r[4], r[5], r[6], r[7]);
    }
    __syncthreads();

    // ---- conv2 (64x64, k=3, pad=1) + bn3 + relu -> bufC (= poolA space) ----
    float (*bufC)[64][8] = (float(*)[64][8])poolA;
    {
        float a2[8] = {0, 0, 0, 0, 0, 0, 0, 0};
        for (int i = 0; i < 64; ++i) {
            const float4 lo = *(const float4*)&bufB[li][i][0];
            const float4 hi = *(const float4*)&bufB[li][i][4];
            const float* wr = w2 + ((size_t)(lane * 64 + i)) * 3;
            const float wk0 = wr[0], wk1 = wr[1], wk2 = wr[2];
            a2[0] += wk1 * lo.x + wk2 * lo.y;
            a2[1] += wk0 * lo.x + wk1 * lo.y + wk2 * lo.z;
            a2[2] += wk0 * lo.y + wk1 * lo.z + wk2 * lo.w;
            a2[3] += wk0 * lo.z + wk1 * lo.w + wk2 * hi.x;
            a2[4] += wk0 * lo.w + wk1 * hi.x + wk2 * hi.y;
            a2[5] += wk0 * hi.x + wk1 * hi.y + wk2 * hi.z;
            a2[6] += wk0 * hi.y + wk1 * hi.z + wk2 * hi.w;
            a2[7] += wk0 * hi.z + wk1 * hi.w;
        }
        const float bb = b2[lane], s = s3[lane], t0 = t3[lane];
        float r[8];
        #pragma unroll
        for (int t = 0; t < 8; ++t) r[t] = fmaxf((a2[t] + bb) * s + t0, 0.f);
        *(float4*)&bufC[li][lane][0] = make_float4(r[0], r[1], r[2], r[3]);
        *(float4*)&bufC[li][lane][4] = make_float4(r[4], r[5], r[6], r[7]);
    }
    __syncthreads();

    // ---- conv3 (128x64) + residual(regs) + relu + fc2 dot ----
    {
        float a3[8] = {0, 0, 0, 0, 0, 0, 0, 0};
        float a4[8] = {0, 0, 0, 0, 0, 0, 0, 0};
        const float* w3a = w3 + c0 * 64;
        const float* w3b = w3 + c1 * 64;
        for (int i = 0; i < 64; i += 4) {
            const float4 wa = *(const float4*)&w3a[i];
            const float4 wb = *(const float4*)&w3b[i];
            const float waq[4] = {wa.x, wa.y, wa.z, wa.w};
            const float wbq[4] = {wb.x, wb.y, wb.z, wb.w};
            #pragma unroll
            for (int qq = 0; qq < 4; ++qq) {
                const float4 lo = *(const float4*)&bufC[li][i + qq][0];
                const float4 hi = *(const float4*)&bufC[li][i + qq][4];
                a3[0] += waq[qq] * lo.x; a3[1] += waq[qq] * lo.y;
                a3[2] += waq[qq] * lo.z; a3[3] += waq[qq] * lo.w;
                a3[4] += waq[qq] * hi.x; a3[5] += waq[qq] * hi.y;
                a3[6] += waq[qq] * hi.z; a3[7] += waq[qq] * hi.w;
                a4[0] += wbq[qq] * lo.x; a4[1] += wbq[qq] * lo.y;
                a4[2] += wbq[qq] * lo.z; a4[3] += wbq[qq] * lo.w;
                a4[4] += wbq[qq] * hi.x; a4[5] += wbq[qq] * hi.y;
                a4[6] += wbq[qq] * hi.z; a4[7] += wbq[qq] * hi.w;
            }
        }
        float partial = 0.f;
        const float ba = b3[c0], bb = b3[c1];
        #pragma unroll
        for (int t = 0; t < 8; ++t) {
            const float v1 = fmaxf(m0[t] + a3[t] + ba, 0.f);
            partial += v1 * fc2w[c0 * 8 + t];
            const float v2 = fmaxf(m1[t] + a4[t] + bb, 0.f);
            partial += v2 * fc2w[c1 * 8 + t];
        }
        #pragma unroll
        for (int off = 32; off > 0; off >>= 1)
            partial += __shfl_down(partial, off, 64);
        if (lane == 0) out[gl4] = partial + fc2b[0];
    }
}

// -------------------------------------------------------------------------
extern "C" void kernel_launch(void* const* d_in, const int* in_sizes, int n_in,
                              void* d_out, int out_size, void* d_ws, size_t ws_size,
                              hipStream_t stream) {
    const float* feature = (const float*)d_in[0];
    const float* lines   = (const float*)d_in[1];
    const float* fc1_w   = (const float*)d_in[2];
    const float* fc1_b   = (const float*)d_in[3];
    const float* bn1g    = (const float*)d_in[4];
    const float* bn1b    = (const float*)d_in[5];
    const float* bn1m    = (const float*)d_in[6];
    const float* bn1v    = (const float*)d_in[7];
    const float* w1      = (const float*)d_in[8];
    const float* b1      = (const float*)d_in[9];
    const float* bn2g    = (const float*)d_in[10];
    const float* bn2b    = (const float*)d_in[11];
    const float* bn2m    = (const float*)d_in[12];
    const float* bn2v    = (const float*)d_in[13];
    const float* w2      = (const float*)d_in[14];
    const float* b2      = (const float*)d_in[15];
    const float* bn3g    = (const float*)d_in[16];
    const float* bn3b    = (const float*)d_in[17];
    const float* bn3m    = (const float*)d_in[18];
    const float* bn3v    = (const float*)d_in[19];
    const float* w3      = (const float*)d_in[20];
    const float* b3      = (const float*)d_in[21];
    const float* fc2w    = (const float*)d_in[22];
    const float* fc2b    = (const float*)d_in[23];

    f16* xmap = (f16*)d_ws;                                     // 32 MiB
    f16* w16  = (f16*)((char*)d_ws + (size_t)32 * 1024 * 1024); // 64 KiB

    wprep_kernel<<<128, 256, 0, stream>>>(fc1_w, w16);
    fc1_mfma<<<1024, 256, 0, stream>>>(feature, w16, fc1_b, xmap);
    loi_kernel<<<4096, 256, 0, stream>>>(xmap, lines,
                                         bn1g, bn1b, bn1m, bn1v, w1, b1,
                                         bn2g, bn2b, bn2m, bn2v, w2, b2,
                                         bn3g, bn3b, bn3m, bn3v, w3, b3,
                                         fc2w, fc2b, (float*)d_out);
}

// Round 3
// 376.188 us; speedup vs baseline: 1.7141x; 1.2846x over previous
//
#include <hip/hip_runtime.h>

#define EPSBN 1e-5f

typedef _Float16 f16;
typedef _Float16 f16x8 __attribute__((ext_vector_type(8)));
typedef _Float16 f16x2 __attribute__((ext_vector_type(2)));
typedef float    f32x4 __attribute__((ext_vector_type(4)));

__device__ inline unsigned int pack2(float a, float b) {
    union { f16x2 h; unsigned int u; } cv;
    cv.h[0] = (f16)a; cv.h[1] = (f16)b;
    return cv.u;
}

// ---------------------------------------------------------------------------
// wprep: convert all weights to f16 in workspace.
// layout (f16 units from wsp): fc1w [0,32768) ; w1 [32768,40960) ;
// w2 as [tau][o][i] [40960,53248) ; w3 [53248,61440)
// ---------------------------------------------------------------------------
__global__ void wprep_kernel(const float* __restrict__ fc1w,
                             const float* __restrict__ w1,
                             const float* __restrict__ w2,
                             const float* __restrict__ w3,
                             f16* __restrict__ dst) {
    const int i = blockIdx.x * 256 + threadIdx.x;   // 61440 total
    float v;
    if (i < 32768)      v = fc1w[i];
    else if (i < 40960) v = w1[i - 32768];
    else if (i < 53248) {
        const int j = i - 40960, tau = j >> 12, rest = j & 4095;
        v = w2[rest * 3 + tau];
    } else              v = w3[i - 53248];
    dst[i] = (f16)v;
}

// ---------------------------------------------------------------------------
// fc1: A = feature (m=p), B = fc1 weights (n=o).  Tile 64p x 128o, K=256.
// Staging prefetched; epilogue via LDS -> coalesced 256B-row stores.
// ---------------------------------------------------------------------------
__global__ __launch_bounds__(256)
void fc1_mfma(const float* __restrict__ feat,   // [8][256][16384]
              const f16*   __restrict__ w16,    // [128][256] f16
              const float* __restrict__ bias,   // [128]
              f16*         __restrict__ xmap) { // [8][16384][128]
    __shared__ f16 lds[64][136];                // staging cols 0..63; epilogue full

    const int tid  = threadIdx.x;
    const int wv   = tid >> 6, lane = tid & 63;
    const int n16  = lane & 15, quad = lane >> 4;
    const int b    = blockIdx.x >> 8;
    const int p0   = (blockIdx.x & 255) * 64;
    const int cp   = tid & 31;    // channel pair in chunk
    const int pg   = tid >> 5;    // p-group of 8

    f32x4 acc[8];
    #pragma unroll
    for (int nt = 0; nt < 8; ++nt) acc[nt] = (f32x4){0.f, 0.f, 0.f, 0.f};

    const float* fbase = feat + (((size_t)b) << 22) + p0 + pg * 8;
    unsigned int* ldsu = (unsigned int*)&lds[0][0];   // row stride 68 dw
    const int wrow = pg * 8;

    float4 c0a, c0b, c1a, c1b;
    {   // load + write chunk 0
        const float* r0 = fbase + (size_t)(2 * cp) * 16384;
        c0a = *(const float4*)(r0);          c0b = *(const float4*)(r0 + 4);
        c1a = *(const float4*)(r0 + 16384);  c1b = *(const float4*)(r0 + 16388);
        ldsu[(wrow + 0) * 68 + cp] = pack2(c0a.x, c1a.x);
        ldsu[(wrow + 1) * 68 + cp] = pack2(c0a.y, c1a.y);
        ldsu[(wrow + 2) * 68 + cp] = pack2(c0a.z, c1a.z);
        ldsu[(wrow + 3) * 68 + cp] = pack2(c0a.w, c1a.w);
        ldsu[(wrow + 4) * 68 + cp] = pack2(c0b.x, c1b.x);
        ldsu[(wrow + 5) * 68 + cp] = pack2(c0b.y, c1b.y);
        ldsu[(wrow + 6) * 68 + cp] = pack2(c0b.z, c1b.z);
        ldsu[(wrow + 7) * 68 + cp] = pack2(c0b.w, c1b.w);
    }

    for (int kc = 0; kc < 4; ++kc) {
        __syncthreads();
        if (kc < 3) {   // prefetch next chunk into registers
            const float* r0 = fbase + (size_t)((kc + 1) * 64 + 2 * cp) * 16384;
            c0a = *(const float4*)(r0);          c0b = *(const float4*)(r0 + 4);
            c1a = *(const float4*)(r0 + 16384);  c1b = *(const float4*)(r0 + 16388);
        }
        #pragma unroll
        for (int ks = 0; ks < 2; ++ks) {
            const f16x8 a = *(const f16x8*)&lds[wv * 16 + n16][ks * 32 + quad * 8];
            #pragma unroll
            for (int nt = 0; nt < 8; ++nt) {
                const f16x8 bf = *(const f16x8*)&w16[(size_t)(nt * 16 + n16) * 256
                                                     + kc * 64 + ks * 32 + quad * 8];
                acc[nt] = __builtin_amdgcn_mfma_f32_16x16x32_f16(a, bf, acc[nt], 0, 0, 0);
            }
        }
        __syncthreads();
        if (kc < 3) {
            ldsu[(wrow + 0) * 68 + cp] = pack2(c0a.x, c1a.x);
            ldsu[(wrow + 1) * 68 + cp] = pack2(c0a.y, c1a.y);
            ldsu[(wrow + 2) * 68 + cp] = pack2(c0a.z, c1a.z);
            ldsu[(wrow + 3) * 68 + cp] = pack2(c0a.w, c1a.w);
            ldsu[(wrow + 4) * 68 + cp] = pack2(c0b.x, c1b.x);
            ldsu[(wrow + 5) * 68 + cp] = pack2(c0b.y, c1b.y);
            ldsu[(wrow + 6) * 68 + cp] = pack2(c0b.z, c1b.z);
            ldsu[(wrow + 7) * 68 + cp] = pack2(c0b.w, c1b.w);
        }
    }
    // (last loop iter ended with __syncthreads(): safe to reuse lds)

    #pragma unroll
    for (int nt = 0; nt < 8; ++nt) {
        const int o = nt * 16 + n16;
        const float bo = bias[o];
        #pragma unroll
        for (int r = 0; r < 4; ++r)
            lds[wv * 16 + quad * 4 + r][o] = (f16)(acc[nt][r] + bo);
    }
    __syncthreads();

    #pragma unroll
    for (int it = 0; it < 4; ++it) {
        const int u = tid + 256 * it;
        const int row = u >> 4, cg = u & 15;
        const float4 v = *(const float4*)&lds[row][cg * 8];
        *(float4*)&xmap[(((size_t)((b << 14) + p0 + row)) << 7) + cg * 8] = v;
    }
}

// ---------------------------------------------------------------------------
// loi: 8 lines/block, 256 thr.  Sampling (wave = 2 lines) -> xp[64n][128c] f16
// -> conv1/conv2(k3,pad1)/conv3 via MFMA -> residual + relu + fc2 reduce.
// ---------------------------------------------------------------------------
__global__ __launch_bounds__(256)
void loi_kernel(const f16*   __restrict__ x,       // [8][16384][128] f16
                const float* __restrict__ lines,
                const f16*   __restrict__ wsp,     // f16 weights (see wprep)
                const float* __restrict__ bn1g, const float* __restrict__ bn1b,
                const float* __restrict__ bn1m, const float* __restrict__ bn1v,
                const float* __restrict__ b1,
                const float* __restrict__ bn2g, const float* __restrict__ bn2b,
                const float* __restrict__ bn2m, const float* __restrict__ bn2v,
                const float* __restrict__ b2,
                const float* __restrict__ bn3g, const float* __restrict__ bn3b,
                const float* __restrict__ bn3m, const float* __restrict__ bn3v,
                const float* __restrict__ b3,
                const float* __restrict__ fc2w, const float* __restrict__ fc2b,
                float* __restrict__ out) {
    __shared__ f16 xp[64][136];                       // raw pooled, [n][c]
    __shared__ union {
        struct { int toff[256][4]; float twgt[256][4]; } tp;   // sampling
        struct { f16 h1[80][72]; f16 h2[64][72]; } cv;         // conv bufs
    } u;
    __shared__ float s1[128], t1[128];
    __shared__ float s2f[64], t2f[64], s3f[64], t3f[64], b1f[64], b2f[64];
    __shared__ float b3f[128], fcw[1024];
    __shared__ float wsum[4][8];

    const f16* w1f16 = wsp + 32768;
    const f16* w2f16 = wsp + 40960;
    const f16* w3f16 = wsp + 53248;

    const int tid  = threadIdx.x;
    const int wv   = tid >> 6, lane = tid & 63;
    const int n16  = lane & 15, quad = lane >> 4;
    const int b    = blockIdx.x >> 8;

    // ---- preamble: LUTs ----
    if (tid < 128) {
        const float s = bn1g[tid] * rsqrtf(bn1v[tid] + EPSBN);
        s1[tid] = s; t1[tid] = bn1b[tid] - bn1m[tid] * s;
    }
    if (tid < 64) {
        const float s = bn2g[tid] * rsqrtf(bn2v[tid] + EPSBN);
        s2f[tid] = s; t2f[tid] = bn2b[tid] - bn2m[tid] * s;
        b1f[tid] = b1[tid];
    } else if (tid < 128) {
        const int c = tid - 64;
        const float s = bn3g[c] * rsqrtf(bn3v[c] + EPSBN);
        s3f[c] = s; t3f[c] = bn3b[c] - bn3m[c] * s;
        b2f[c] = b2[c];
    } else {
        b3f[tid - 128] = b3[tid - 128];
    }
    *(float4*)&fcw[tid * 4] = *(const float4*)&fc2w[tid * 4];

    // ---- tuples: one per (line, pt) ----
    {
        const int li = tid >> 5, pt = tid & 31;
        const int gl = blockIdx.x * 8 + li;
        const float4 ln = *(const float4*)&lines[gl * 4];
        const float lam = (float)pt * (1.0f / 31.0f);
        const float px = ln.x * lam + ln.z * (1.f - lam) - 0.5f;
        const float py = ln.y * lam + ln.w * (1.f - lam) - 0.5f;
        const float px0 = fminf(fmaxf(floorf(px), 0.f), 127.f);
        const float py0 = fminf(fmaxf(floorf(py), 0.f), 127.f);
        const float px1 = fminf(px0 + 1.f, 127.f);
        const float py1 = fminf(py0 + 1.f, 127.f);
        const int ix0 = (int)px0, iy0 = (int)py0;
        const int ix1 = (int)px1, iy1 = (int)py1;
        u.tp.toff[tid][0] = (((ix0 << 7) + iy0) << 7);
        u.tp.toff[tid][1] = (((ix1 << 7) + iy0) << 7);
        u.tp.toff[tid][2] = (((ix0 << 7) + iy1) << 7);
        u.tp.toff[tid][3] = (((ix1 << 7) + iy1) << 7);
        const float wx1 = px1 - px, wx0 = px - px0;
        const float wy1 = py1 - py, wy0 = py - py0;
        u.tp.twgt[tid][0] = wx1 * wy1; u.tp.twgt[tid][1] = wx0 * wy1;
        u.tp.twgt[tid][2] = wx1 * wy0; u.tp.twgt[tid][3] = wx0 * wy0;
    }
    __syncthreads();   // B1

    // ---- sampling + maxpool: wave wv -> lines 2wv, 2wv+1; lane -> ch pair ----
    {
        const f16* xbh = x + (((size_t)b) << 21) + lane * 2;
        unsigned int* xpu = (unsigned int*)&xp[0][0];   // stride 68 dw
        for (int lsub = 0; lsub < 2; ++lsub) {
            const int li = wv * 2 + lsub;
            #pragma unroll
            for (int t = 0; t < 8; ++t) {
                float m0 = -3.4e38f, m1 = -3.4e38f;
                #pragma unroll
                for (int s = 0; s < 4; ++s) {
                    const int combo = li * 32 + t * 4 + s;
                    const int4   off = *(const int4*)&u.tp.toff[combo][0];
                    const float4 wg  = *(const float4*)&u.tp.twgt[combo][0];
                    const f16x2 g00 = *(const f16x2*)(xbh + off.x);
                    const f16x2 g10 = *(const f16x2*)(xbh + off.y);
                    const f16x2 g01 = *(const f16x2*)(xbh + off.z);
                    const f16x2 g11 = *(const f16x2*)(xbh + off.w);
                    const float v0 = (float)g00[0] * wg.x + (float)g10[0] * wg.y
                                   + (float)g01[0] * wg.z + (float)g11[0] * wg.w;
                    const float v1 = (float)g00[1] * wg.x + (float)g10[1] * wg.y
                                   + (float)g01[1] * wg.z + (float)g11[1] * wg.w;
                    m0 = fmaxf(m0, v0); m1 = fmaxf(m1, v1);
                }
                xpu[(li * 8 + t) * 68 + lane] = pack2(m0, m1);
            }
        }
    }
    __syncthreads();   // B2 (tuples dead; xp ready)

    // ---- zero h1 guard rows (t=-1 and t=8 per line) ----
    {
        const int r = tid >> 4, seg = tid & 15;
        const int row = (r >> 1) * 10 + (r & 1) * 9;
        *(unsigned long long*)&u.cv.h1[row][seg * 4] = 0ull;
    }

    // ---- conv1: [64o x 128c] x [128c x 64n], bn1+relu fused into B-frags ----
    {
        const int o_lane = wv * 16 + n16;
        f32x4 acc1[4];
        #pragma unroll
        for (int nt = 0; nt < 4; ++nt) acc1[nt] = (f32x4){0.f, 0.f, 0.f, 0.f};
        #pragma unroll
        for (int ks = 0; ks < 4; ++ks) {
            const int k = ks * 32 + quad * 8;
            const f16x8 a = *(const f16x8*)&w1f16[o_lane * 128 + k];
            const float4 sa = *(const float4*)&s1[k], sb = *(const float4*)&s1[k + 4];
            const float4 ta = *(const float4*)&t1[k], tb = *(const float4*)&t1[k + 4];
            #pragma unroll
            for (int nt = 0; nt < 4; ++nt) {
                const f16x8 raw = *(const f16x8*)&xp[nt * 16 + n16][k];
                f16x8 bf;
                bf[0] = (f16)fmaxf((float)raw[0] * sa.x + ta.x, 0.f);
                bf[1] = (f16)fmaxf((float)raw[1] * sa.y + ta.y, 0.f);
                bf[2] = (f16)fmaxf((float)raw[2] * sa.z + ta.z, 0.f);
                bf[3] = (f16)fmaxf((float)raw[3] * sa.w + ta.w, 0.f);
                bf[4] = (f16)fmaxf((float)raw[4] * sb.x + tb.x, 0.f);
                bf[5] = (f16)fmaxf((float)raw[5] * sb.y + tb.y, 0.f);
                bf[6] = (f16)fmaxf((float)raw[6] * sb.z + tb.z, 0.f);
                bf[7] = (f16)fmaxf((float)raw[7] * sb.w + tb.w, 0.f);
                acc1[nt] = __builtin_amdgcn_mfma_f32_16x16x32_f16(a, bf, acc1[nt], 0, 0, 0);
            }
        }
        // bn2+relu -> h1 padded columns
        #pragma unroll
        for (int nt = 0; nt < 4; ++nt) {
            const int n = nt * 16 + n16;
            const int nprow = (n >> 3) * 10 + (n & 7) + 1;
            #pragma unroll
            for (int r = 0; r < 4; ++r) {
                const int o = wv * 16 + quad * 4 + r;
                const float v = fmaxf((acc1[nt][r] + b1f[o]) * s2f[o] + t2f[o], 0.f);
                u.cv.h1[nprow][o] = (f16)v;
            }
        }
    }
    __syncthreads();   // B3

    // ---- conv2: 3 shifted [64o x 64i] matmuls over padded h1 ----
    {
        const int o_lane = wv * 16 + n16;
        f32x4 acc2[4];
        #pragma unroll
        for (int nt = 0; nt < 4; ++nt) acc2[nt] = (f32x4){0.f, 0.f, 0.f, 0.f};
        #pragma unroll
        for (int d = 0; d < 3; ++d) {
            const f16* A2 = w2f16 + d * 4096;
            #pragma unroll
            for (int ks = 0; ks < 2; ++ks) {
                const int k = ks * 32 + quad * 8;
                const f16x8 a = *(const f16x8*)&A2[o_lane * 64 + k];
                #pragma unroll
                for (int nt = 0; nt < 4; ++nt) {
                    const int n = nt * 16 + n16;
                    const int row = (n >> 3) * 10 + (n & 7) + d;
                    const f16x8 bf = *(const f16x8*)&u.cv.h1[row][k];
                    acc2[nt] = __builtin_amdgcn_mfma_f32_16x16x32_f16(a, bf, acc2[nt], 0, 0, 0);
                }
            }
        }
        // bn3+relu -> h2 [n][o]
        #pragma unroll
        for (int nt = 0; nt < 4; ++nt) {
            const int n = nt * 16 + n16;
            #pragma unroll
            for (int r = 0; r < 4; ++r) {
                const int o = wv * 16 + quad * 4 + r;
                const float v = fmaxf((acc2[nt][r] + b2f[o]) * s3f[o] + t3f[o], 0.f);
                u.cv.h2[n][o] = (f16)v;
            }
        }
    }
    __syncthreads();   // B4

    // ---- conv3: [128o x 64i] + residual + relu + fc2 partial ----
    {
        f32x4 acc3[2][4];
        #pragma unroll
        for (int h = 0; h < 2; ++h)
            #pragma unroll
            for (int nt = 0; nt < 4; ++nt) acc3[h][nt] = (f32x4){0.f, 0.f, 0.f, 0.f};
        #pragma unroll
        for (int ks = 0; ks < 2; ++ks) {
            const int k = ks * 32 + quad * 8;
            const f16x8 a0 = *(const f16x8*)&w3f16[(wv * 16 + n16) * 64 + k];
            const f16x8 a1 = *(const f16x8*)&w3f16[(64 + wv * 16 + n16) * 64 + k];
            #pragma unroll
            for (int nt = 0; nt < 4; ++nt) {
                const f16x8 bf = *(const f16x8*)&u.cv.h2[nt * 16 + n16][k];
                acc3[0][nt] = __builtin_amdgcn_mfma_f32_16x16x32_f16(a0, bf, acc3[0][nt], 0, 0, 0);
                acc3[1][nt] = __builtin_amdgcn_mfma_f32_16x16x32_f16(a1, bf, acc3[1][nt], 0, 0, 0);
            }
        }
        float part0 = 0.f, part1 = 0.f, part2 = 0.f, part3 = 0.f;
        #pragma unroll
        for (int h = 0; h < 2; ++h) {
            #pragma unroll
            for (int nt = 0; nt < 4; ++nt) {
                const int n = nt * 16 + n16;
                float p = 0.f;
                #pragma unroll
                for (int r = 0; r < 4; ++r) {
                    const int o = h * 64 + wv * 16 + quad * 4 + r;
                    float v = acc3[h][nt][r] + b3f[o] + (float)xp[n][o];
                    v = fmaxf(v, 0.f);
                    p += v * fcw[o * 8 + (n & 7)];
                }
                if (nt == 0) part0 += p; else if (nt == 1) part1 += p;
                else if (nt == 2) part2 += p; else part3 += p;
            }
        }
        // butterfly over lane bits {0,1,2,4,5} (preserve bit3 = line parity)
        #pragma unroll
        for (int off_i = 0; off_i < 5; ++off_i) {
            const int off = (int[]){1, 2, 4, 16, 32}[off_i];
            part0 += __shfl_xor(part0, off, 64);
            part1 += __shfl_xor(part1, off, 64);
            part2 += __shfl_xor(part2, off, 64);
            part3 += __shfl_xor(part3, off, 64);
        }
        if ((lane & 55) == 0) {          // lanes 0 and 8
            const int par = (lane >> 3) & 1;
            wsum[wv][0 + par] = part0;
            wsum[wv][2 + par] = part1;
            wsum[wv][4 + par] = part2;
            wsum[wv][6 + par] = part3;
        }
    }
    __syncthreads();   // B5

    if (tid < 8) {
        const float s = wsum[0][tid] + wsum[1][tid] + wsum[2][tid] + wsum[3][tid];
        out[blockIdx.x * 8 + tid] = s + fc2b[0];
    }
}

// ---------------------------------------------------------------------------
extern "C" void kernel_launch(void* const* d_in, const int* in_sizes, int n_in,
                              void* d_out, int out_size, void* d_ws, size_t ws_size,
                              hipStream_t stream) {
    const float* feature = (const float*)d_in[0];
    const float* lines   = (const float*)d_in[1];
    const float* fc1_w   = (const float*)d_in[2];
    const float* fc1_b   = (const float*)d_in[3];
    const float* bn1g    = (const float*)d_in[4];
    const float* bn1b    = (const float*)d_in[5];
    const float* bn1m    = (const float*)d_in[6];
    const float* bn1v    = (const float*)d_in[7];
    const float* w1      = (const float*)d_in[8];
    const float* b1      = (const float*)d_in[9];
    const float* bn2g    = (const float*)d_in[10];
    const float* bn2b    = (const float*)d_in[11];
    const float* bn2m    = (const float*)d_in[12];
    const float* bn2v    = (const float*)d_in[13];
    const float* w2      = (const float*)d_in[14];
    const float* b2      = (const float*)d_in[15];
    const float* bn3g    = (const float*)d_in[16];
    const float* bn3b    = (const float*)d_in[17];
    const float* bn3m    = (const float*)d_in[18];
    const float* bn3v    = (const float*)d_in[19];
    const float* w3      = (const float*)d_in[20];
    const float* b3      = (const float*)d_in[21];
    const float* fc2w    = (const float*)d_in[22];
    const float* fc2b    = (const float*)d_in[23];

    f16* xmap = (f16*)d_ws;                                      // 32 MiB
    f16* wsp  = (f16*)((char*)d_ws + (size_t)32 * 1024 * 1024);  // 120 KiB

    wprep_kernel<<<240, 256, 0, stream>>>(fc1_w, w1, w2, w3, wsp);
    fc1_mfma<<<2048, 256, 0, stream>>>(feature, wsp, fc1_b, xmap);
    loi_kernel<<<2048, 256, 0, stream>>>(xmap, lines, wsp,
                                         bn1g, bn1b, bn1m, bn1v, b1,
                                         bn2g, bn2b, bn2m, bn2v, b2,
                                         bn3g, bn3b, bn3m, bn3v, b3,
                                         fc2w, fc2b, (float*)d_out);
}

// Round 4
// 323.236 us; speedup vs baseline: 1.9948x; 1.1638x over previous
//
#include <hip/hip_runtime.h>

#define EPSBN 1e-5f

typedef _Float16 f16;
typedef _Float16 f16x8 __attribute__((ext_vector_type(8)));
typedef _Float16 f16x4 __attribute__((ext_vector_type(4)));
typedef _Float16 f16x2 __attribute__((ext_vector_type(2)));
typedef float    f32x4 __attribute__((ext_vector_type(4)));

__device__ inline unsigned int pack2(float a, float b) {
    union { f16x2 h; unsigned int u; } cv;
    cv.h[0] = (f16)a; cv.h[1] = (f16)b;
    return cv.u;
}
__device__ inline f16x4 hmax4(f16x4 a, f16x4 b) {
    f16x4 r;
    #pragma unroll
    for (int i = 0; i < 4; ++i) r[i] = a[i] > b[i] ? a[i] : b[i];
    return r;
}
__device__ inline f16x8 relu8(f16x8 v) {
    f16x8 r;
    #pragma unroll
    for (int i = 0; i < 8; ++i) r[i] = v[i] > (f16)0.f ? v[i] : (f16)0.f;
    return r;
}

// ---------------------------------------------------------------------------
// wprep: weights -> f16.  fc1w [0,32768) ; w1 [32768,40960) ;
// w2 as [tau][o][i] [40960,53248) ; w3 [53248,61440)
// ---------------------------------------------------------------------------
__global__ void wprep_kernel(const float* __restrict__ fc1w,
                             const float* __restrict__ w1,
                             const float* __restrict__ w2,
                             const float* __restrict__ w3,
                             f16* __restrict__ dst) {
    const int i = blockIdx.x * 256 + threadIdx.x;   // 61440 total
    float v;
    if (i < 32768)      v = fc1w[i];
    else if (i < 40960) v = w1[i - 32768];
    else if (i < 53248) {
        const int j = i - 40960, tau = j >> 12, rest = j & 4095;
        v = w2[rest * 3 + tau];
    } else              v = w3[i - 53248];
    dst[i] = (f16)v;
}

// ---------------------------------------------------------------------------
// fc1: tile 64p x 128o, K=256.  image = blockIdx & 7  (XCD-pinned so the
// 4 MB per-image output stays in that XCD's L2 for the loi gathers).
// ---------------------------------------------------------------------------
__global__ __launch_bounds__(256)
void fc1_mfma(const float* __restrict__ feat,   // [8][256][16384]
              const f16*   __restrict__ w16,    // [128][256] f16
              const float* __restrict__ bias,   // [128]
              f16*         __restrict__ xmap) { // [8][16384][128]
    __shared__ f16 lds[64][136];

    const int tid  = threadIdx.x;
    const int wv   = tid >> 6, lane = tid & 63;
    const int n16  = lane & 15, quad = lane >> 4;
    const int b    = blockIdx.x & 7;             // XCD swizzle
    const int p0   = (blockIdx.x >> 3) * 64;
    const int cp   = tid & 31;
    const int pg   = tid >> 5;

    f32x4 acc[8];
    #pragma unroll
    for (int nt = 0; nt < 8; ++nt) acc[nt] = (f32x4){0.f, 0.f, 0.f, 0.f};

    const float* fbase = feat + (((size_t)b) << 22) + p0 + pg * 8;
    unsigned int* ldsu = (unsigned int*)&lds[0][0];   // row stride 68 dw
    const int wrow = pg * 8;

    float4 c0a, c0b, c1a, c1b;
    {
        const float* r0 = fbase + (size_t)(2 * cp) * 16384;
        c0a = *(const float4*)(r0);          c0b = *(const float4*)(r0 + 4);
        c1a = *(const float4*)(r0 + 16384);  c1b = *(const float4*)(r0 + 16388);
        ldsu[(wrow + 0) * 68 + cp] = pack2(c0a.x, c1a.x);
        ldsu[(wrow + 1) * 68 + cp] = pack2(c0a.y, c1a.y);
        ldsu[(wrow + 2) * 68 + cp] = pack2(c0a.z, c1a.z);
        ldsu[(wrow + 3) * 68 + cp] = pack2(c0a.w, c1a.w);
        ldsu[(wrow + 4) * 68 + cp] = pack2(c0b.x, c1b.x);
        ldsu[(wrow + 5) * 68 + cp] = pack2(c0b.y, c1b.y);
        ldsu[(wrow + 6) * 68 + cp] = pack2(c0b.z, c1b.z);
        ldsu[(wrow + 7) * 68 + cp] = pack2(c0b.w, c1b.w);
    }

    for (int kc = 0; kc < 4; ++kc) {
        __syncthreads();
        if (kc < 3) {
            const float* r0 = fbase + (size_t)((kc + 1) * 64 + 2 * cp) * 16384;
            c0a = *(const float4*)(r0);          c0b = *(const float4*)(r0 + 4);
            c1a = *(const float4*)(r0 + 16384);  c1b = *(const float4*)(r0 + 16388);
        }
        #pragma unroll
        for (int ks = 0; ks < 2; ++ks) {
            const f16x8 a = *(const f16x8*)&lds[wv * 16 + n16][ks * 32 + quad * 8];
            #pragma unroll
            for (int nt = 0; nt < 8; ++nt) {
                const f16x8 bf = *(const f16x8*)&w16[(size_t)(nt * 16 + n16) * 256
                                                     + kc * 64 + ks * 32 + quad * 8];
                acc[nt] = __builtin_amdgcn_mfma_f32_16x16x32_f16(a, bf, acc[nt], 0, 0, 0);
            }
        }
        __syncthreads();
        if (kc < 3) {
            ldsu[(wrow + 0) * 68 + cp] = pack2(c0a.x, c1a.x);
            ldsu[(wrow + 1) * 68 + cp] = pack2(c0a.y, c1a.y);
            ldsu[(wrow + 2) * 68 + cp] = pack2(c0a.z, c1a.z);
            ldsu[(wrow + 3) * 68 + cp] = pack2(c0a.w, c1a.w);
            ldsu[(wrow + 4) * 68 + cp] = pack2(c0b.x, c1b.x);
            ldsu[(wrow + 5) * 68 + cp] = pack2(c0b.y, c1b.y);
            ldsu[(wrow + 6) * 68 + cp] = pack2(c0b.z, c1b.z);
            ldsu[(wrow + 7) * 68 + cp] = pack2(c0b.w, c1b.w);
        }
    }

    #pragma unroll
    for (int nt = 0; nt < 8; ++nt) {
        const int o = nt * 16 + n16;
        const float bo = bias[o];
        #pragma unroll
        for (int r = 0; r < 4; ++r)
            lds[wv * 16 + quad * 4 + r][o] = (f16)(acc[nt][r] + bo);
    }
    __syncthreads();

    #pragma unroll
    for (int it = 0; it < 4; ++it) {
        const int u = tid + 256 * it;
        const int row = u >> 4, cg = u & 15;
        const float4 v = *(const float4*)&lds[row][cg * 8];
        *(float4*)&xmap[(((size_t)((b << 14) + p0 + row)) << 7) + cg * 8] = v;
    }
}

// ---------------------------------------------------------------------------
// loi: 8 lines/block, image = blockIdx & 7 (XCD-pinned: gathers stay in the
// XCD L2 that fc1 just filled).  Sampling in packed f16 (4 ch/lane, 8B loads)
// -> xp[64n][128c] f16 -> conv1/conv2/conv3 MFMA -> residual+relu+fc2.
// ---------------------------------------------------------------------------
__global__ __launch_bounds__(256)
void loi_kernel(const f16*   __restrict__ x,       // [8][16384][128] f16
                const float* __restrict__ lines,
                const f16*   __restrict__ wsp,
                const float* __restrict__ bn1g, const float* __restrict__ bn1b,
                const float* __restrict__ bn1m, const float* __restrict__ bn1v,
                const float* __restrict__ b1,
                const float* __restrict__ bn2g, const float* __restrict__ bn2b,
                const float* __restrict__ bn2m, const float* __restrict__ bn2v,
                const float* __restrict__ b2,
                const float* __restrict__ bn3g, const float* __restrict__ bn3b,
                const float* __restrict__ bn3m, const float* __restrict__ bn3v,
                const float* __restrict__ b3,
                const float* __restrict__ fc2w, const float* __restrict__ fc2b,
                float* __restrict__ out) {
    __shared__ f16 xp[64][136];                       // 17408 B
    __shared__ alignas(16) union {
        struct { int toff[256][4]; f16 twgt[256][4]; } tp;     // 6144 B
        struct { f16 h1[80][72]; f16 h2[64][72]; } cv;         // 20736 B
    } u;
    __shared__ f16 s1h[128], t1h[128];                // 512 B
    __shared__ float s2f[64], t2f[64], s3f[64], t3f[64], b1f[64], b2f[64];
    __shared__ float b3f[128];
    __shared__ float wsum[4][8];

    const f16* w1f16 = wsp + 32768;
    const f16* w2f16 = wsp + 40960;
    const f16* w3f16 = wsp + 53248;

    const int tid  = threadIdx.x;
    const int wv   = tid >> 6, lane = tid & 63;
    const int n16  = lane & 15, quad = lane >> 4;
    const int img  = blockIdx.x & 7;                  // XCD swizzle
    const int mblk = blockIdx.x >> 3;                 // 0..255 within image

    // ---- LUTs ----
    if (tid < 128) {
        const float s = bn1g[tid] * rsqrtf(bn1v[tid] + EPSBN);
        s1h[tid] = (f16)s; t1h[tid] = (f16)(bn1b[tid] - bn1m[tid] * s);
    }
    if (tid < 64) {
        const float s = bn2g[tid] * rsqrtf(bn2v[tid] + EPSBN);
        s2f[tid] = s; t2f[tid] = bn2b[tid] - bn2m[tid] * s;
        b1f[tid] = b1[tid];
    } else if (tid < 128) {
        const int c = tid - 64;
        const float s = bn3g[c] * rsqrtf(bn3v[c] + EPSBN);
        s3f[c] = s; t3f[c] = bn3b[c] - bn3m[c] * s;
        b2f[c] = b2[c];
    } else {
        b3f[tid - 128] = b3[tid - 128];
    }

    // ---- interp tuples: one per (line, pt) ----
    {
        const int li = tid >> 5, pt = tid & 31;
        const int gl = img * 2048 + mblk * 8 + li;
        const float4 ln = *(const float4*)&lines[gl * 4];
        const float lam = (float)pt * (1.0f / 31.0f);
        const float px = ln.x * lam + ln.z * (1.f - lam) - 0.5f;
        const float py = ln.y * lam + ln.w * (1.f - lam) - 0.5f;
        const float px0 = fminf(fmaxf(floorf(px), 0.f), 127.f);
        const float py0 = fminf(fmaxf(floorf(py), 0.f), 127.f);
        const float px1 = fminf(px0 + 1.f, 127.f);
        const float py1 = fminf(py0 + 1.f, 127.f);
        const int ix0 = (int)px0, iy0 = (int)py0;
        const int ix1 = (int)px1, iy1 = (int)py1;
        u.tp.toff[tid][0] = (((ix0 << 7) + iy0) << 7);
        u.tp.toff[tid][1] = (((ix1 << 7) + iy0) << 7);
        u.tp.toff[tid][2] = (((ix0 << 7) + iy1) << 7);
        u.tp.toff[tid][3] = (((ix1 << 7) + iy1) << 7);
        const float wx1 = px1 - px, wx0 = px - px0;
        const float wy1 = py1 - py, wy0 = py - py0;
        u.tp.twgt[tid][0] = (f16)(wx1 * wy1); u.tp.twgt[tid][1] = (f16)(wx0 * wy1);
        u.tp.twgt[tid][2] = (f16)(wx1 * wy0); u.tp.twgt[tid][3] = (f16)(wx0 * wy0);
    }
    __syncthreads();   // B1

    // ---- sampling + maxpool, packed f16: lane -> 4 channels, half-wave -> line ----
    {
        const int h = lane >> 5, j = lane & 31;     // line parity, channel group
        const int li = wv * 2 + h;
        const f16* xbh = x + (((size_t)img) << 21) + 4 * j;
        #pragma unroll
        for (int t = 0; t < 8; ++t) {
            f16x4 m = {(f16)(-60000.f), (f16)(-60000.f), (f16)(-60000.f), (f16)(-60000.f)};
            #pragma unroll
            for (int s = 0; s < 4; ++s) {
                const int combo = li * 32 + t * 4 + s;
                const int4  off = *(const int4*)&u.tp.toff[combo][0];
                const f16x4 tw  = *(const f16x4*)&u.tp.twgt[combo][0];
                const f16x4 g00 = *(const f16x4*)(xbh + off.x);
                const f16x4 g10 = *(const f16x4*)(xbh + off.y);
                const f16x4 g01 = *(const f16x4*)(xbh + off.z);
                const f16x4 g11 = *(const f16x4*)(xbh + off.w);
                const f16x4 w0 = {tw[0], tw[0], tw[0], tw[0]};
                const f16x4 w1v = {tw[1], tw[1], tw[1], tw[1]};
                const f16x4 w2v = {tw[2], tw[2], tw[2], tw[2]};
                const f16x4 w3v = {tw[3], tw[3], tw[3], tw[3]};
                f16x4 v = g00 * w0 + g10 * w1v + g01 * w2v + g11 * w3v;
                m = hmax4(m, v);
            }
            *(f16x4*)&xp[li * 8 + t][4 * j] = m;
        }
    }
    __syncthreads();   // B2 (tuples dead; xp ready)

    // ---- zero h1 guard rows ----
    {
        const int r = tid >> 4, seg = tid & 15;
        const int row = (r >> 1) * 10 + (r & 1) * 9;
        *(unsigned long long*)&u.cv.h1[row][seg * 4] = 0ull;
    }

    // ---- conv1 + fused bn1/relu (packed f16) ----
    {
        const int o_lane = wv * 16 + n16;
        f32x4 acc1[4];
        #pragma unroll
        for (int nt = 0; nt < 4; ++nt) acc1[nt] = (f32x4){0.f, 0.f, 0.f, 0.f};
        #pragma unroll
        for (int ks = 0; ks < 4; ++ks) {
            const int k = ks * 32 + quad * 8;
            const f16x8 a  = *(const f16x8*)&w1f16[o_lane * 128 + k];
            const f16x8 s8 = *(const f16x8*)&s1h[k];
            const f16x8 t8 = *(const f16x8*)&t1h[k];
            #pragma unroll
            for (int nt = 0; nt < 4; ++nt) {
                const f16x8 raw = *(const f16x8*)&xp[nt * 16 + n16][k];
                const f16x8 bf = relu8(raw * s8 + t8);
                acc1[nt] = __builtin_amdgcn_mfma_f32_16x16x32_f16(a, bf, acc1[nt], 0, 0, 0);
            }
        }
        #pragma unroll
        for (int nt = 0; nt < 4; ++nt) {
            const int n = nt * 16 + n16;
            const int nprow = (n >> 3) * 10 + (n & 7) + 1;
            #pragma unroll
            for (int r = 0; r < 4; ++r) {
                const int o = wv * 16 + quad * 4 + r;
                const float v = fmaxf((acc1[nt][r] + b1f[o]) * s2f[o] + t2f[o], 0.f);
                u.cv.h1[nprow][o] = (f16)v;
            }
        }
    }
    __syncthreads();   // B3

    // ---- conv2: 3 shifted [64x64] matmuls ----
    {
        const int o_lane = wv * 16 + n16;
        f32x4 acc2[4];
        #pragma unroll
        for (int nt = 0; nt < 4; ++nt) acc2[nt] = (f32x4){0.f, 0.f, 0.f, 0.f};
        #pragma unroll
        for (int d = 0; d < 3; ++d) {
            const f16* A2 = w2f16 + d * 4096;
            #pragma unroll
            for (int ks = 0; ks < 2; ++ks) {
                const int k = ks * 32 + quad * 8;
                const f16x8 a = *(const f16x8*)&A2[o_lane * 64 + k];
                #pragma unroll
                for (int nt = 0; nt < 4; ++nt) {
                    const int n = nt * 16 + n16;
                    const int row = (n >> 3) * 10 + (n & 7) + d;
                    const f16x8 bf = *(const f16x8*)&u.cv.h1[row][k];
                    acc2[nt] = __builtin_amdgcn_mfma_f32_16x16x32_f16(a, bf, acc2[nt], 0, 0, 0);
                }
            }
        }
        #pragma unroll
        for (int nt = 0; nt < 4; ++nt) {
            const int n = nt * 16 + n16;
            #pragma unroll
            for (int r = 0; r < 4; ++r) {
                const int o = wv * 16 + quad * 4 + r;
                const float v = fmaxf((acc2[nt][r] + b2f[o]) * s3f[o] + t3f[o], 0.f);
                u.cv.h2[n][o] = (f16)v;
            }
        }
    }
    __syncthreads();   // B4

    // ---- conv3 + residual + relu + fc2 ----
    {
        // per-lane fc2 weights: (n&7) == n16&7 is lane-constant -> 8 scalars
        const int col = n16 & 7, obase = wv * 16 + quad * 4;
        float fcv[2][4];
        #pragma unroll
        for (int h = 0; h < 2; ++h)
            #pragma unroll
            for (int r = 0; r < 4; ++r)
                fcv[h][r] = fc2w[(h * 64 + obase + r) * 8 + col];

        f32x4 acc3[2][4];
        #pragma unroll
        for (int h = 0; h < 2; ++h)
            #pragma unroll
            for (int nt = 0; nt < 4; ++nt) acc3[h][nt] = (f32x4){0.f, 0.f, 0.f, 0.f};
        #pragma unroll
        for (int ks = 0; ks < 2; ++ks) {
            const int k = ks * 32 + quad * 8;
            const f16x8 a0 = *(const f16x8*)&w3f16[(wv * 16 + n16) * 64 + k];
            const f16x8 a1 = *(const f16x8*)&w3f16[(64 + wv * 16 + n16) * 64 + k];
            #pragma unroll
            for (int nt = 0; nt < 4; ++nt) {
                const f16x8 bf = *(const f16x8*)&u.cv.h2[nt * 16 + n16][k];
                acc3[0][nt] = __builtin_amdgcn_mfma_f32_16x16x32_f16(a0, bf, acc3[0][nt], 0, 0, 0);
                acc3[1][nt] = __builtin_amdgcn_mfma_f32_16x16x32_f16(a1, bf, acc3[1][nt], 0, 0, 0);
            }
        }
        float part[4] = {0.f, 0.f, 0.f, 0.f};
        #pragma unroll
        for (int h = 0; h < 2; ++h) {
            const float4 bq = *(const float4*)&b3f[h * 64 + obase];
            const float bqa[4] = {bq.x, bq.y, bq.z, bq.w};
            #pragma unroll
            for (int nt = 0; nt < 4; ++nt) {
                const int n = nt * 16 + n16;
                const f16x4 rx = *(const f16x4*)&xp[n][h * 64 + obase];
                float p = 0.f;
                #pragma unroll
                for (int r = 0; r < 4; ++r) {
                    float v = acc3[h][nt][r] + bqa[r] + (float)rx[r];
                    v = fmaxf(v, 0.f);
                    p += v * fcv[h][r];
                }
                part[nt] += p;
            }
        }
        #pragma unroll
        for (int off_i = 0; off_i < 5; ++off_i) {
            const int off = (int[]){1, 2, 4, 16, 32}[off_i];
            part[0] += __shfl_xor(part[0], off, 64);
            part[1] += __shfl_xor(part[1], off, 64);
            part[2] += __shfl_xor(part[2], off, 64);
            part[3] += __shfl_xor(part[3], off, 64);
        }
        if ((lane & 55) == 0) {          // lanes 0 and 8
            const int par = (lane >> 3) & 1;
            wsum[wv][0 + par] = part[0];
            wsum[wv][2 + par] = part[1];
            wsum[wv][4 + par] = part[2];
            wsum[wv][6 + par] = part[3];
        }
    }
    __syncthreads();   // B5

    if (tid < 8) {
        const float s = wsum[0][tid] + wsum[1][tid] + wsum[2][tid] + wsum[3][tid];
        out[img * 2048 + mblk * 8 + tid] = s + fc2b[0];
    }
}

// ---------------------------------------------------------------------------
extern "C" void kernel_launch(void* const* d_in, const int* in_sizes, int n_in,
                              void* d_out, int out_size, void* d_ws, size_t ws_size,
                              hipStream_t stream) {
    const float* feature = (const float*)d_in[0];
    const float* lines   = (const float*)d_in[1];
    const float* fc1_w   = (const float*)d_in[2];
    const float* fc1_b   = (const float*)d_in[3];
    const float* bn1g    = (const float*)d_in[4];
    const float* bn1b    = (const float*)d_in[5];
    const float* bn1m    = (const float*)d_in[6];
    const float* bn1v    = (const float*)d_in[7];
    const float* w1      = (const float*)d_in[8];
    const float* b1      = (const float*)d_in[9];
    const float* bn2g    = (const float*)d_in[10];
    const float* bn2b    = (const float*)d_in[11];
    const float* bn2m    = (const float*)d_in[12];
    const float* bn2v    = (const float*)d_in[13];
    const float* w2      = (const float*)d_in[14];
    const float* b2      = (const float*)d_in[15];
    const float* bn3g    = (const float*)d_in[16];
    const float* bn3b    = (const float*)d_in[17];
    const float* bn3m    = (const float*)d_in[18];
    const float* bn3v    = (const float*)d_in[19];
    const float* w3      = (const float*)d_in[20];
    const float* b3      = (const float*)d_in[21];
    const float* fc2w    = (const float*)d_in[22];
    const float* fc2b    = (const float*)d_in[23];

    f16* xmap = (f16*)d_ws;                                      // 32 MiB
    f16* wsp  = (f16*)((char*)d_ws + (size_t)32 * 1024 * 1024);  // 120 KiB

    wprep_kernel<<<240, 256, 0, stream>>>(fc1_w, w1, w2, w3, wsp);
    fc1_mfma<<<2048, 256, 0, stream>>>(feature, wsp, fc1_b, xmap);
    loi_kernel<<<2048, 256, 0, stream>>>(xmap, lines, wsp,
                                         bn1g, bn1b, bn1m, bn1v, b1,
                                         bn2g, bn2b, bn2m, bn2v, b2,
                                         bn3g, bn3b, bn3m, bn3v, b3,
                                         fc2w, fc2b, (float*)d_out);
}